// Round 2
// baseline (1153.399 us; speedup 1.0000x reference)
//
#include <hip/hip_runtime.h>
#include <stdint.h>

typedef unsigned short u16;
typedef short v8s __attribute__((ext_vector_type(8)));   // 8 x bf16 (4 VGPRs)
typedef float v4f __attribute__((ext_vector_type(4)));   // 4 x f32

#define NTOK 4096
#define DDIM 2048
#define HDIM 1792
#define NEXP 8
#define SHROWS 4096        /* shared-expert slots: rows 0..4095, token = slot   */
#define MAXROWS 14336      /* 4096 shared + up to 10240 routed (256-padded)    */
#define MAXT256 56         /* MAXROWS / 256 */
#define MAXT128 112        /* MAXROWS / 128 (fallback kernel) */

__device__ __forceinline__ u16 f2b(float f) {
    union { float f; uint32_t i; } v; v.f = f;
    uint32_t r = v.i + 0x7fff + ((v.i >> 16) & 1);   // RNE
    return (u16)(r >> 16);
}
__device__ __forceinline__ float silu_f(float x) { return x / (1.f + __expf(-x)); }
__device__ __forceinline__ float b2f(u16 u) {
    union { float f; uint32_t i; } v; v.i = ((uint32_t)u) << 16; return v.f;
}

#define AS1 __attribute__((address_space(1)))
#define AS3 __attribute__((address_space(3)))
__device__ __forceinline__ void gload_lds16(const u16* g, u16* l) {
    __builtin_amdgcn_global_load_lds((const AS1 void*)g, (AS3 void*)l, 16, 0, 0);
}
#define WAITV(n) asm volatile("s_waitcnt vmcnt(" #n ")" ::: "memory")

// f32 -> bf16 bulk convert (n % 4 == 0)
__global__ void cvt_kernel(const float* __restrict__ in, u16* __restrict__ out, int n) {
    int i = (blockIdx.x * blockDim.x + threadIdx.x) * 4;
    if (i >= n) return;
    float4 v = *(const float4*)(in + i);
    ushort4 o;
    o.x = f2b(v.x); o.y = f2b(v.y); o.z = f2b(v.z); o.w = f2b(v.w);
    *(ushort4*)(out + i) = o;
}

// ---------------- router: 1 wave per token, all f32 ----------------
__global__ void router_kernel(const float* __restrict__ x, const float* __restrict__ gw,
                              const float* __restrict__ bias,
                              int* __restrict__ topk_idx, float* __restrict__ topk_wt,
                              int* __restrict__ cnt) {
    int wave = threadIdx.x >> 6, lane = threadIdx.x & 63;
    int t = blockIdx.x * 4 + wave;
    float acc[NEXP];
#pragma unroll
    for (int e = 0; e < NEXP; e++) acc[e] = 0.f;
    const float* xr = x + (size_t)t * DDIM;
    for (int i = 0; i < DDIM / 64; i++) {
        int d = i * 64 + lane;
        float xv = xr[d];
#pragma unroll
        for (int e = 0; e < NEXP; e++) acc[e] += xv * gw[e * DDIM + d];
    }
#pragma unroll
    for (int off = 32; off > 0; off >>= 1)
#pragma unroll
        for (int e = 0; e < NEXP; e++) acc[e] += __shfl_xor(acc[e], off, 64);
    if (lane == 0) {
        float s[NEXP], sb[NEXP];
#pragma unroll
        for (int e = 0; e < NEXP; e++) {
            s[e] = 1.f / (1.f + __expf(-acc[e]));
            sb[e] = s[e] + bias[e];
        }
        int i0 = 0;
#pragma unroll
        for (int e = 1; e < NEXP; e++) if (sb[e] > sb[i0]) i0 = e;   // ties -> lowest idx
        int i1 = -1;
#pragma unroll
        for (int e = 0; e < NEXP; e++) {
            if (e == i0) continue;
            if (i1 < 0 || sb[e] > sb[i1]) i1 = e;
        }
        float w0 = s[i0], w1 = s[i1];
        float inv = 1.f / (w0 + w1 + 1e-20f);
        topk_idx[t * 2] = i0; topk_idx[t * 2 + 1] = i1;
        topk_wt[t * 2] = w0 * inv; topk_wt[t * 2 + 1] = w1 * inv;
        atomicAdd(&cnt[i0], 1); atomicAdd(&cnt[i1], 1);
    }
}

__global__ void zero_small(int* cnt, int* cnt2) {
    if (threadIdx.x < NEXP) { cnt[threadIdx.x] = 0; cnt2[threadIdx.x] = 0; }
}

// prefix (256-aligned routed segments after 4096 shared slots), tile->expert maps,
// init slot lists: shared slots = identity/weight 1, rest = {tok 0, wt 0}.
__global__ void setup_kernel(const int* __restrict__ cnt, int* __restrict__ base,
                             int* __restrict__ exp_tile256, int* __restrict__ exp_tile128,
                             int* __restrict__ tok_of, float* __restrict__ wt_of) {
    if (threadIdx.x == 0) {
        int b = SHROWS, sb[NEXP + 1];
        for (int e = 0; e < NEXP; e++) { sb[e] = b; base[e] = b; b += (cnt[e] + 255) & ~255; }
        sb[NEXP] = b;
        for (int td = 0; td < MAXT256; td++) {
            int e = -1, r = td << 8;
            if (r < SHROWS) e = NEXP;                 // shared tiles
            else for (int q = 0; q < NEXP; q++)
                if (r >= sb[q] && r < sb[q + 1]) e = q;
            exp_tile256[td] = e;
        }
        for (int td = 0; td < MAXT128; td++) {
            int e = -1, r = td << 7;
            if (r < SHROWS) e = NEXP;
            else for (int q = 0; q < NEXP; q++)
                if (r >= sb[q] && r < sb[q + 1]) e = q;
            exp_tile128[td] = e;
        }
    }
    __syncthreads();
    for (int i = threadIdx.x; i < MAXROWS; i += blockDim.x) {
        tok_of[i] = (i < SHROWS) ? i : 0;
        wt_of[i]  = (i < SHROWS) ? 1.f : 0.f;
    }
}

__global__ void assign_kernel(const int* __restrict__ topk_idx, const float* __restrict__ topk_wt,
                              const int* __restrict__ base, int* __restrict__ cnt2,
                              int* __restrict__ tok_of, float* __restrict__ wt_of) {
    int g = blockIdx.x * blockDim.x + threadIdx.x;   // 0..8191
    int t = g >> 1, k = g & 1;
    int e = topk_idx[t * 2 + k];
    int p = base[e] + atomicAdd(&cnt2[e], 1);
    tok_of[p] = t; wt_of[p] = topk_wt[t * 2 + k];
}

// ============ 256x256xK GEMM NT, BK=32, ring-4 LDS, counted vmcnt ============
// C[M,N] = A[M,K] @ B[N,K]^T. A,B bf16. 512 thr = 8 waves (2M x 4N),
// per-wave 128x64 output (8x4 16x16 frags). LDS ring of 4 K-tiles, each
// A[256x32]+B[256x32] packed-pair layout [128 LDSrows][8 chunks of 16B],
// chunk slot s = cc ^ (R&7), cc = ((row&1)<<2)|colchunk  (conflict-free reads,
// linear global_load_lds dest with pre-swizzled global source).
// Schedule (T3+T4+T5): stage tile t+3 while computing tile t; vmcnt(12) keeps
// 3 tiles (12 loads/thread) in flight across raw s_barriers; setprio on MFMA.
// B expert select: row-block tile mt -> e = exp_tile[mt], B base = Bw + e*bstride
// (e = NEXP is the shared expert: arrays hold 9 expert slots).
// EPI: 0 = store bf16 at [row*N+col]; 2 = atomicAdd f32 into Cout[tok_of[row]*N+col]
template <int EPI, bool GATHER, int K>
__global__ __launch_bounds__(512, 2)
void gemm256(const u16* __restrict__ A, const u16* __restrict__ Bw,
             void* __restrict__ Cout, int N,
             const int* __restrict__ tok_of, const int* __restrict__ exp_tile,
             long bstride) {
    constexpr int NT = K / 32;
    int nt = blockIdx.x, mt = blockIdx.y;
    int e = exp_tile[mt];
    if (e < 0) return;                         // unused padded tile
    const u16* Bp = Bw + (size_t)e * bstride;
    int m0 = mt * 256, n0 = nt * 256;

    __shared__ u16 smem[4 * 2 * 8192];         // [ring][A/B][128*64] = 128 KiB
    int tid = threadIdx.x, lane = tid & 63, wave = tid >> 6;
    int wm = wave >> 2, wn = wave & 3, quad = lane >> 4, lr = lane & 15;

    v4f acc[8][4];
#pragma unroll
    for (int i = 0; i < 8; i++)
#pragma unroll
        for (int j = 0; j < 4; j++) acc[i][j] = (v4f){0.f, 0.f, 0.f, 0.f};

    // ---- staging descriptors (2 A-chunks + 2 B-chunks per thread) ----
    const u16* gA[2]; const u16* gB[2]; int ldso[2];
#pragma unroll
    for (int j = 0; j < 2; j++) {
        int idx = j * 512 + tid;               // linear 16B-chunk 0..1023
        int R = idx >> 3, s = idx & 7, cc = s ^ (R & 7);
        int r = (R << 1) | (cc >> 2);          // real row 0..255
        int col = (cc & 3) * 8;                // k-offset within BK=32
        int ar = GATHER ? tok_of[m0 + r] : (m0 + r);
        gA[j] = A + (size_t)ar * K + col;
        gB[j] = Bp + (size_t)(n0 + r) * K + col;
        ldso[j] = (j * 512 + wave * 64) * 8;   // wave-uniform u16 offset
    }
    // ---- fragment ds_read offsets (u16 units within one operand slab) ----
    int offA[8], offB[4];
#pragma unroll
    for (int mi = 0; mi < 8; mi++) {
        int r = wm * 128 + mi * 16 + lr;
        int R = r >> 1, cc = ((r & 1) << 2) | quad;
        offA[mi] = R * 64 + ((cc ^ (R & 7)) << 3);
    }
#pragma unroll
    for (int ni = 0; ni < 4; ni++) {
        int r = wn * 64 + ni * 16 + lr;
        int R = r >> 1, cc = ((r & 1) << 2) | quad;
        offB[ni] = R * 64 + ((cc ^ (R & 7)) << 3);
    }

    auto STAGE = [&](int t) {
        u16* base = smem + (t & 3) * 16384;
        int k0 = t * 32;
#pragma unroll
        for (int j = 0; j < 2; j++) gload_lds16(gA[j] + k0, base + ldso[j]);
#pragma unroll
        for (int j = 0; j < 2; j++) gload_lds16(gB[j] + k0, base + 8192 + ldso[j]);
    };

    STAGE(0); STAGE(1); STAGE(2);              // prologue: 3 tiles in flight

#pragma unroll 1
    for (int t = 0; t < NT; t++) {
        if (t + 3 < NT) STAGE(t + 3);
        // wait for own tile-t loads: 12 = 3 tiles x 4 loads still outstanding
        if      (t + 3 < NT) { WAITV(12); }
        else if (t + 2 < NT) { WAITV(8); }
        else if (t + 1 < NT) { WAITV(4); }
        else                 { WAITV(0); }
        __builtin_amdgcn_s_barrier();          // all waves' tile-t loads landed
        const u16* sa = smem + (t & 3) * 16384;
        const u16* sb = sa + 8192;
        v8s af[8], bfr[4];
#pragma unroll
        for (int mi = 0; mi < 8; mi++) af[mi] = *(const v8s*)(sa + offA[mi]);
#pragma unroll
        for (int ni = 0; ni < 4; ni++) bfr[ni] = *(const v8s*)(sb + offB[ni]);
        asm volatile("s_waitcnt lgkmcnt(0)" ::: "memory");
        __builtin_amdgcn_sched_barrier(0);
        __builtin_amdgcn_s_setprio(1);
#pragma unroll
        for (int mi = 0; mi < 8; mi++)
#pragma unroll
            for (int ni = 0; ni < 4; ni++)
                acc[mi][ni] = __builtin_amdgcn_mfma_f32_16x16x32_bf16(af[mi], bfr[ni], acc[mi][ni], 0, 0, 0);
        __builtin_amdgcn_s_setprio(0);
        __builtin_amdgcn_s_barrier();          // reads of ring[t&3] done -> next
                                               //   phase may stage into it (t+4)
    }

#pragma unroll
    for (int mi = 0; mi < 8; mi++)
#pragma unroll
        for (int ni = 0; ni < 4; ni++)
#pragma unroll
            for (int r = 0; r < 4; r++) {
                int gr = m0 + wm * 128 + mi * 16 + quad * 4 + r;
                int gc = n0 + wn * 64 + ni * 16 + lr;
                float v = acc[mi][ni][r];
                if (EPI == 0) {
                    ((u16*)Cout)[(size_t)gr * N + gc] = f2b(v);
                } else {
                    int tok = tok_of[gr];      // pad rows: tok=0, v==0 -> harmless
                    atomicAdd(&((float*)Cout)[(size_t)tok * N + gc], v);
                }
            }
}

// ---------- fallback 128x128x64 GEMM, f32 B converted on the fly ----------
// (used only when workspace can't hold bf16 weight copies)
template <int EPI, bool GATHER>
__global__ __launch_bounds__(256, 2)
void gemm_nt_f32(const u16* __restrict__ A, const float* __restrict__ Bw,
                 const float* __restrict__ Bsh, void* __restrict__ Cout, int N, int K,
                 const int* __restrict__ tok_of, const int* __restrict__ exp_tile,
                 long bstride) {
    int nt = blockIdx.x, mt = blockIdx.y;
    int e = exp_tile[mt];
    if (e < 0) return;
    const float* Bp = (e == NEXP) ? Bsh : (Bw + (size_t)e * bstride);
    int m0 = mt * 128, n0 = nt * 128;
    __shared__ u16 As[128 * 64];
    __shared__ u16 Bs[128 * 64];
    int tid = threadIdx.x, lane = tid & 63, wave = tid >> 6;
    int wm = wave >> 1, wn = wave & 1;
    int quad = lane >> 4, lr = lane & 15;

    v4f acc[4][4];
#pragma unroll
    for (int i = 0; i < 4; i++)
#pragma unroll
        for (int j = 0; j < 4; j++) acc[i][j] = (v4f){0.f, 0.f, 0.f, 0.f};

    const u16* gA[4]; const float* fB[4]; u16* sB[4]; u16* lA[4];
#pragma unroll
    for (int j = 0; j < 4; j++) {
        int idx = j * 256 + tid;
        int row = idx >> 3, s = idx & 7, cc = s ^ (row & 7);
        int arow = GATHER ? tok_of[m0 + row] : (m0 + row);
        gA[j] = A + (size_t)arow * K + cc * 8;
        fB[j] = Bp + (size_t)(n0 + row) * K + cc * 8;
        sB[j] = Bs + (size_t)idx * 8;
        lA[j] = As + (j * 256 + wave * 64) * 8;
    }

    for (int k0 = 0; k0 < K; k0 += 64) {
#pragma unroll
        for (int j = 0; j < 4; j++) gload_lds16(gA[j] + k0, lA[j]);
#pragma unroll
        for (int j = 0; j < 4; j++) {
            const float* bp = fB[j] + k0;
            float4 f0 = *(const float4*)bp;
            float4 f1 = *(const float4*)(bp + 4);
            union { v8s v; u16 s[8]; } u;
            u.s[0] = f2b(f0.x); u.s[1] = f2b(f0.y); u.s[2] = f2b(f0.z); u.s[3] = f2b(f0.w);
            u.s[4] = f2b(f1.x); u.s[5] = f2b(f1.y); u.s[6] = f2b(f1.z); u.s[7] = f2b(f1.w);
            *(v8s*)sB[j] = u.v;
        }
        __syncthreads();
#pragma unroll
        for (int kk = 0; kk < 64; kk += 32) {
            v8s af[4], bfr[4];
#pragma unroll
            for (int mi = 0; mi < 4; mi++) {
                int row = wm * 64 + mi * 16 + lr;
                int c = (kk >> 3) + quad;
                af[mi] = *(const v8s*)(As + row * 64 + ((c ^ (row & 7)) << 3));
            }
#pragma unroll
            for (int ni = 0; ni < 4; ni++) {
                int row = wn * 64 + ni * 16 + lr;
                int c = (kk >> 3) + quad;
                bfr[ni] = *(const v8s*)(Bs + row * 64 + ((c ^ (row & 7)) << 3));
            }
#pragma unroll
            for (int mi = 0; mi < 4; mi++)
#pragma unroll
                for (int ni = 0; ni < 4; ni++)
                    acc[mi][ni] = __builtin_amdgcn_mfma_f32_16x16x32_bf16(af[mi], bfr[ni], acc[mi][ni], 0, 0, 0);
        }
        __syncthreads();
    }

#pragma unroll
    for (int mi = 0; mi < 4; mi++)
#pragma unroll
        for (int ni = 0; ni < 4; ni++)
#pragma unroll
            for (int r = 0; r < 4; r++) {
                int gr = m0 + wm * 64 + mi * 16 + quad * 4 + r;
                int gc = n0 + wn * 64 + ni * 16 + lr;
                float v = acc[mi][ni][r];
                if (EPI == 0) {
                    ((u16*)Cout)[(size_t)gr * N + gc] = f2b(v);
                } else {
                    int tok = tok_of[gr];
                    atomicAdd(&((float*)Cout)[(size_t)tok * N + gc], v);
                }
            }
}

// h = silu(w*u1) * (w*u3), written IN PLACE into u1. per-row w.
__global__ void swiglu_kernel(u16* __restrict__ u1, const u16* __restrict__ u3,
                              const float* __restrict__ wt_of) {
    int row = blockIdx.x;
    float w = wt_of[row];
    size_t i = (size_t)row * HDIM + threadIdx.x * 4;
    ushort4 a = *(const ushort4*)(u1 + i);
    ushort4 b = *(const ushort4*)(u3 + i);
    ushort4 o;
    o.x = f2b(silu_f(w * b2f(a.x)) * (w * b2f(b.x)));
    o.y = f2b(silu_f(w * b2f(a.y)) * (w * b2f(b.y)));
    o.z = f2b(silu_f(w * b2f(a.z)) * (w * b2f(b.z)));
    o.w = f2b(silu_f(w * b2f(a.w)) * (w * b2f(b.w)));
    *(ushort4*)(u1 + i) = o;
}

__global__ void aux_kernel(float* __restrict__ out) {
    if (threadIdx.x == 0) out[(size_t)NTOK * DDIM] = 0.f;   // aux_loss
}

extern "C" void kernel_launch(void* const* d_in, const int* in_sizes, int n_in,
                              void* d_out, int out_size, void* d_ws, size_t ws_size,
                              hipStream_t stream) {
    const float* x   = (const float*)d_in[0];
    const float* gw  = (const float*)d_in[1];
    const float* w1s = (const float*)d_in[2];
    const float* w2s = (const float*)d_in[3];
    const float* w3s = (const float*)d_in[4];
    const float* w1e = (const float*)d_in[5];
    const float* w2e = (const float*)d_in[6];
    const float* w3e = (const float*)d_in[7];
    const float* ebias = (const float*)d_in[8];
    float* outp = (float*)d_out;

    char* ws = (char*)d_ws;
    size_t off = 0;
    auto alloc = [&](size_t bytes) {
        void* p = ws + off;
        off = (off + bytes + 255) & ~(size_t)255;
        return p;
    };
    u16* xb     = (u16*)alloc((size_t)NTOK * DDIM * 2);          // 16.8 MB
    u16* u1     = (u16*)alloc((size_t)MAXROWS * HDIM * 2);       // 51.4 MB
    u16* u3     = (u16*)alloc((size_t)MAXROWS * HDIM * 2);       // 51.4 MB
    int* topk_idx = (int*)alloc(NTOK * 2 * 4);
    float* topk_wt = (float*)alloc(NTOK * 2 * 4);
    int* cnt    = (int*)alloc(64);
    int* cnt2   = (int*)alloc(64);
    int* base   = (int*)alloc(64);
    int* exp_tile256 = (int*)alloc(MAXT256 * 4);
    int* exp_tile128 = (int*)alloc(MAXT128 * 4);
    int* tok_of = (int*)alloc(MAXROWS * 4);
    float* wt_of = (float*)alloc(MAXROWS * 4);
    // 9-expert bf16 weight arrays (slot 8 = shared expert)
    const int SH = HDIM * DDIM;                  // 3670016
    const int EX8 = 8 * SH;                      // 29360128
    u16* w1eb = (u16*)alloc((size_t)9 * SH * 2); // 66.1 MB
    u16* w2eb = (u16*)alloc((size_t)9 * SH * 2);
    u16* w3eb = (u16*)alloc((size_t)9 * SH * 2);
    bool full = (off <= ws_size);
    (void)in_sizes; (void)n_in; (void)out_size;

    hipMemsetAsync(outp, 0, (size_t)NTOK * DDIM * sizeof(float), stream);
    zero_small<<<1, 64, 0, stream>>>(cnt, cnt2);
    router_kernel<<<NTOK / 4, 256, 0, stream>>>(x, gw, ebias, topk_idx, topk_wt, cnt);
    setup_kernel<<<1, 256, 0, stream>>>(cnt, base, exp_tile256, exp_tile128, tok_of, wt_of);
    assign_kernel<<<NTOK * 2 / 256, 256, 0, stream>>>(topk_idx, topk_wt, base, cnt2, tok_of, wt_of);

    cvt_kernel<<<(NTOK * DDIM / 4 + 255) / 256, 256, 0, stream>>>(x, xb, NTOK * DDIM);
    if (full) {
        cvt_kernel<<<(EX8 / 4 + 255) / 256, 256, 0, stream>>>(w1e, w1eb, EX8);
        cvt_kernel<<<(SH / 4 + 255) / 256, 256, 0, stream>>>(w1s, w1eb + (size_t)8 * SH, SH);
        cvt_kernel<<<(EX8 / 4 + 255) / 256, 256, 0, stream>>>(w2e, w2eb, EX8);
        cvt_kernel<<<(SH / 4 + 255) / 256, 256, 0, stream>>>(w2s, w2eb + (size_t)8 * SH, SH);
        cvt_kernel<<<(EX8 / 4 + 255) / 256, 256, 0, stream>>>(w3e, w3eb, EX8);
        cvt_kernel<<<(SH / 4 + 255) / 256, 256, 0, stream>>>(w3s, w3eb + (size_t)8 * SH, SH);

        gemm256<0, true, DDIM><<<dim3(HDIM / 256, MAXT256), 512, 0, stream>>>(
            xb, w1eb, u1, HDIM, tok_of, exp_tile256, (long)SH);
        gemm256<0, true, DDIM><<<dim3(HDIM / 256, MAXT256), 512, 0, stream>>>(
            xb, w3eb, u3, HDIM, tok_of, exp_tile256, (long)SH);
        swiglu_kernel<<<MAXROWS, 448, 0, stream>>>(u1, u3, wt_of);
        gemm256<2, false, HDIM><<<dim3(DDIM / 256, MAXT256), 512, 0, stream>>>(
            u1, w2eb, outp, DDIM, tok_of, exp_tile256, (long)SH);
    } else {
        // fallback: 128-tile kernels, f32 B converted during staging
        gemm_nt_f32<0, true><<<dim3(HDIM / 128, MAXT128), 256, 0, stream>>>(
            xb, w1e, w1s, u1, HDIM, DDIM, tok_of, exp_tile128, (long)SH);
        gemm_nt_f32<0, true><<<dim3(HDIM / 128, MAXT128), 256, 0, stream>>>(
            xb, w3e, w3s, u3, HDIM, DDIM, tok_of, exp_tile128, (long)SH);
        swiglu_kernel<<<MAXROWS, 448, 0, stream>>>(u1, u3, wt_of);
        gemm_nt_f32<2, false><<<dim3(DDIM / 128, MAXT128), 256, 0, stream>>>(
            u1, w2e, w2s, outp, DDIM, HDIM, tok_of, exp_tile128, (long)SH);
    }

    aux_kernel<<<1, 64, 0, stream>>>(outp);
}